// Round 1
// baseline (317.000 us; speedup 1.0000x reference)
//
#include <hip/hip_runtime.h>

// WindowMSA fused kernel for MI355X (gfx950).
// One block = one window (B=4096). 4 waves = 4 heads, each wave owns its head
// END-TO-END: QKV (two passes, x read direct from global), attention with all
// transposes via a wave-private LDS scratch (sequential aliasing), proj GEMM.
// R4: LDS 38,912 B => 4 blocks/CU; exactly ONE __syncthreads per block.

typedef __bf16 bf16_t;
typedef __bf16 bf8v  __attribute__((ext_vector_type(8)));
typedef float  f4v   __attribute__((ext_vector_type(4)));

#define QK_SCALE 0.17677669529663687f  // 1/sqrt(32)

__device__ __forceinline__ f4v mfma16(bf8v a, bf8v b, f4v c) {
  return __builtin_amdgcn_mfma_f32_16x16x32_bf16(a, b, c, 0, 0, 0);
}

// ---------------- prep: swizzle weights to B-fragment order, build CB ----------------
// wq: [t<24][kt<4][lane<64][j<8]  = bf16(qkv_w[t*16+(l&15)][kt*32+(l>>4)*8+j])
// wp: [t<8 ][kt<4][lane<64][j<8]  = bf16(proj_w[...same...])
// cbs: [w<64][h<4][n<64][l16<16][nt<4] fp32 = bias+mask at m = nt*16+l16
//      (-1e30 for m>=49; 0 for n>=49,m<49) -- MFMA lane order => float4 loads.
__global__ void prep_kernel(const float* __restrict__ mask,
                            const float* __restrict__ qkv_w,
                            const float* __restrict__ proj_w,
                            const float* __restrict__ bias_table,
                            bf16_t* __restrict__ wq,
                            bf16_t* __restrict__ wp,
                            float* __restrict__ cbs) {
  const int stride = gridDim.x * blockDim.x;
  const int tid0 = blockIdx.x * blockDim.x + threadIdx.x;
  for (int i = tid0; i < 24 * 4 * 64 * 8; i += stride) {
    int j = i & 7, l = (i >> 3) & 63, kt = (i >> 9) & 3, t = i >> 11;
    int n = t * 16 + (l & 15), k = kt * 32 + (l >> 4) * 8 + j;
    wq[i] = (bf16_t)qkv_w[n * 128 + k];
  }
  for (int i = tid0; i < 8 * 4 * 64 * 8; i += stride) {
    int j = i & 7, l = (i >> 3) & 63, kt = (i >> 9) & 3, t = i >> 11;
    int n = t * 16 + (l & 15), k = kt * 32 + (l >> 4) * 8 + j;
    wp[i] = (bf16_t)proj_w[n * 128 + k];
  }
  for (int i = tid0; i < 64 * 4 * 64 * 64; i += stride) {
    int j = i & 63;                 // l16*4 + nt
    int l16 = j >> 2, nt = j & 3;
    int m = nt * 16 + l16;
    int n = (i >> 6) & 63, h = (i >> 12) & 3, w = i >> 14;
    float v;
    if (m >= 49) {
      v = -1e30f;                    // mask out padded key columns
    } else if (n >= 49) {
      v = 0.0f;                      // padded query rows: benign logits
    } else {
      int cn = 13 * (n / 7) + n % 7;
      int mm = 48 - m;
      int cm = 13 * (mm / 7) + mm % 7;
      v = bias_table[(cn + cm) * 4 + h] + mask[(w * 49 + n) * 49 + m];
    }
    cbs[i] = v;
  }
}

// ---------------- fused window MSA ----------------
__global__ __launch_bounds__(256, 4) void msa_kernel(
    const float* __restrict__ x,
    const float* __restrict__ qkv_b,
    const float* __restrict__ proj_b,
    const bf16_t* __restrict__ wq,
    const bf16_t* __restrict__ wp,
    const float* __restrict__ cbs,
    float* __restrict__ out) {
  // Per-wave slab (wave h == head h), 4864 bf16 = 9,728 B:
  //   T  [64][40]  (2560 el): scratch, sequentially hosts K -> Q -> P(half0)
  //                           -> P(half1) -> O. Wave-private until the single
  //                           barrier; proj reads all 4 T slabs after it.
  //   VT [32][72]  (2304 el): V^T[d][token], live from pass-2 epilogue to PV.
  // Strides 40/72 el keep every b128 fragment read 16B-aligned & ~2-way banks.
  __shared__ __align__(16) bf16_t sl[4][4864];

#define TT(hh, r, c)  sl[hh][(r) * 40 + (c)]
#define VTT(hh, d, m) sl[hh][2560 + (d) * 72 + (m)]

  const int tid = threadIdx.x;
  const int wv  = tid >> 6;   // wave 0..3 == head
  const int ln  = tid & 63;
  const int l16 = ln & 15;
  const int l4  = ln >> 4;    // 0..3
  const int b   = blockIdx.x;
  const int w   = b & 63;     // mask window index
  const int h   = wv;

  const float* xb = x + (size_t)b * (49 * 128);

  // A-fragment loader: x[tok][kt*32 + l4*8 .. +7], zeros for padded tokens.
  auto load_a = [&](int mt, int kt) -> bf8v {
    int tok = mt * 16 + l16;
    const float* p = xb + (tok < 49 ? tok * 128 : 0) + kt * 32 + l4 * 8;
    float4 u0 = *(const float4*)p;
    float4 u1 = *(const float4*)(p + 4);
    if (tok >= 49) { u0 = make_float4(0.f, 0.f, 0.f, 0.f); u1 = u0; }
    bf8v t = { (bf16_t)u0.x, (bf16_t)u0.y, (bf16_t)u0.z, (bf16_t)u0.w,
               (bf16_t)u1.x, (bf16_t)u1.y, (bf16_t)u1.z, (bf16_t)u1.w };
    return t;
  };

  // ---- pass 1: Q_h, K_h  (M=64 tokens, N=64 ch, K=128) ----
  f4v acc[4][4];   // [ti: 0,1 = Q d-tiles; 2,3 = K d-tiles][mt]
#pragma unroll
  for (int ti = 0; ti < 4; ++ti)
#pragma unroll
    for (int mt = 0; mt < 4; ++mt) acc[ti][mt] = (f4v){0.f, 0.f, 0.f, 0.f};
#pragma unroll
  for (int kt = 0; kt < 4; ++kt) {
    bf8v a[4];
#pragma unroll
    for (int mt = 0; mt < 4; ++mt) a[mt] = load_a(mt, kt);
    bf8v bb[4];
#pragma unroll
    for (int ti = 0; ti < 4; ++ti) {
      int t = (ti < 2) ? (2 * h + ti) : (8 + 2 * h + (ti - 2));
      bb[ti] = *(const bf8v*)(wq + (((t * 4 + kt) * 64 + ln) << 3));
    }
#pragma unroll
    for (int ti = 0; ti < 4; ++ti)
#pragma unroll
      for (int mt = 0; mt < 4; ++mt)
        acc[ti][mt] = mfma16(a[mt], bb[ti], acc[ti][mt]);
  }

  // ---- K -> T -> kf frags ----
  bf8v kf[4], qf[4];
#pragma unroll
  for (int ti = 0; ti < 2; ++ti) {
    float bias = qkv_b[128 + 32 * h + ti * 16 + l16];
#pragma unroll
    for (int mt = 0; mt < 4; ++mt)
#pragma unroll
      for (int r = 0; r < 4; ++r)
        TT(h, mt * 16 + l4 * 4 + r, ti * 16 + l16) = (bf16_t)(acc[2 + ti][mt][r] + bias);
  }
#pragma unroll
  for (int mt = 0; mt < 4; ++mt)
    kf[mt] = *(const bf8v*)&TT(h, mt * 16 + l16, l4 * 8);

  // ---- Q -> T -> qf frags (overwrites K copy; in-wave DS order guarantees) ----
#pragma unroll
  for (int ti = 0; ti < 2; ++ti) {
    float bias = qkv_b[32 * h + ti * 16 + l16];
#pragma unroll
    for (int mt = 0; mt < 4; ++mt)
#pragma unroll
      for (int r = 0; r < 4; ++r)
        TT(h, mt * 16 + l4 * 4 + r, ti * 16 + l16) =
            (bf16_t)((acc[ti][mt][r] + bias) * QK_SCALE);
  }
#pragma unroll
  for (int mt = 0; mt < 4; ++mt)
    qf[mt] = *(const bf8v*)&TT(h, mt * 16 + l16, l4 * 8);

  // ---- pass 2: V_h ----
  f4v vacc[2][4];
#pragma unroll
  for (int ti = 0; ti < 2; ++ti)
#pragma unroll
    for (int mt = 0; mt < 4; ++mt) vacc[ti][mt] = (f4v){0.f, 0.f, 0.f, 0.f};
#pragma unroll
  for (int kt = 0; kt < 4; ++kt) {
    bf8v a[4];
#pragma unroll
    for (int mt = 0; mt < 4; ++mt) a[mt] = load_a(mt, kt);
    bf8v bb[2];
#pragma unroll
    for (int ti = 0; ti < 2; ++ti) {
      int t = 16 + 2 * h + ti;
      bb[ti] = *(const bf8v*)(wq + (((t * 4 + kt) * 64 + ln) << 3));
    }
#pragma unroll
    for (int ti = 0; ti < 2; ++ti)
#pragma unroll
      for (int mt = 0; mt < 4; ++mt)
        vacc[ti][mt] = mfma16(a[mt], bb[ti], vacc[ti][mt]);
  }
  // V^T epilogue: VT[d][token]
#pragma unroll
  for (int ti = 0; ti < 2; ++ti) {
    float bias = qkv_b[256 + 32 * h + ti * 16 + l16];
#pragma unroll
    for (int mt = 0; mt < 4; ++mt)
#pragma unroll
      for (int r = 0; r < 4; ++r)
        VTT(h, ti * 16 + l16, mt * 16 + l4 * 4 + r) = (bf16_t)(vacc[ti][mt][r] + bias);
  }

  // ---- QK^T: C[query][key], lane holds row=mt*16+l4*4+r, col=nt*16+l16 ----
  f4v lg[4][4];
#pragma unroll
  for (int mt = 0; mt < 4; ++mt)
#pragma unroll
    for (int nt = 0; nt < 4; ++nt)
      lg[mt][nt] = mfma16(qf[mt], kf[nt], (f4v){0.f, 0.f, 0.f, 0.f});

  // ---- softmax (max-free, clamped): half0 (m<32) -> T, half1 kept in regs ----
  const float* cbp = cbs + ((size_t)(w * 4 + h) << 12);
  float ph1[4][4][2];
#pragma unroll
  for (int mt = 0; mt < 4; ++mt) {
#pragma unroll
    for (int r = 0; r < 4; ++r) {
      int row = mt * 16 + l4 * 4 + r;
      float4 cbv = *(const float4*)(cbp + (row << 6) + l16 * 4);
      float v0 = __expf(fmaxf(lg[mt][0][r] + cbv.x, -80.f));
      float v1 = __expf(fmaxf(lg[mt][1][r] + cbv.y, -80.f));
      float v2 = __expf(fmaxf(lg[mt][2][r] + cbv.z, -80.f));
      float v3 = __expf(fmaxf(lg[mt][3][r] + cbv.w, -80.f));
      float s = (v0 + v1) + (v2 + v3);
#pragma unroll
      for (int off = 1; off < 16; off <<= 1) s += __shfl_xor(s, off);
      float inv = 1.0f / s;
      TT(h, row, l16)      = (bf16_t)(v0 * inv);
      TT(h, row, 16 + l16) = (bf16_t)(v1 * inv);
      ph1[mt][r][0] = v2 * inv;
      ph1[mt][r][1] = v3 * inv;
    }
  }

  // ---- PV: O[token][d] = P @ V, two k-halves through T ----
  f4v oc[4][2];
#pragma unroll
  for (int nt = 0; nt < 4; ++nt)
#pragma unroll
    for (int dt = 0; dt < 2; ++dt) oc[nt][dt] = (f4v){0.f, 0.f, 0.f, 0.f};
  {
    bf8v pf[4], vf[2];
#pragma unroll
    for (int nt = 0; nt < 4; ++nt) pf[nt] = *(const bf8v*)&TT(h, nt * 16 + l16, l4 * 8);
#pragma unroll
    for (int dt = 0; dt < 2; ++dt) vf[dt] = *(const bf8v*)&VTT(h, dt * 16 + l16, l4 * 8);
#pragma unroll
    for (int nt = 0; nt < 4; ++nt)
#pragma unroll
      for (int dt = 0; dt < 2; ++dt) oc[nt][dt] = mfma16(pf[nt], vf[dt], oc[nt][dt]);
    // stage half1 (m in 32..63) over T
#pragma unroll
    for (int mt = 0; mt < 4; ++mt)
#pragma unroll
      for (int r = 0; r < 4; ++r) {
        int row = mt * 16 + l4 * 4 + r;
        TT(h, row, l16)      = (bf16_t)ph1[mt][r][0];
        TT(h, row, 16 + l16) = (bf16_t)ph1[mt][r][1];
      }
#pragma unroll
    for (int nt = 0; nt < 4; ++nt) pf[nt] = *(const bf8v*)&TT(h, nt * 16 + l16, l4 * 8);
#pragma unroll
    for (int dt = 0; dt < 2; ++dt) vf[dt] = *(const bf8v*)&VTT(h, dt * 16 + l16, 32 + l4 * 8);
#pragma unroll
    for (int nt = 0; nt < 4; ++nt)
#pragma unroll
      for (int dt = 0; dt < 2; ++dt) oc[nt][dt] = mfma16(pf[nt], vf[dt], oc[nt][dt]);
  }
  // O -> T (cols 0..31 of head's slab)
#pragma unroll
  for (int nt = 0; nt < 4; ++nt)
#pragma unroll
    for (int dt = 0; dt < 2; ++dt)
#pragma unroll
      for (int r = 0; r < 4; ++r)
        TT(h, nt * 16 + l4 * 4 + r, dt * 16 + l16) = (bf16_t)(oc[nt][dt][r]);

  __syncthreads();   // the only block-wide barrier: O slabs -> proj

  // ---- proj GEMM (M=64, N=128, K=128); wave handles 2 n-tiles ----
  {
    f4v pacc[4][2];
#pragma unroll
    for (int mt = 0; mt < 4; ++mt)
#pragma unroll
      for (int nj = 0; nj < 2; ++nj) pacc[mt][nj] = (f4v){0.f, 0.f, 0.f, 0.f};
#pragma unroll
    for (int kt = 0; kt < 4; ++kt) {
      bf8v a[4];
#pragma unroll
      for (int mt = 0; mt < 4; ++mt)
        a[mt] = *(const bf8v*)&TT(kt, mt * 16 + l16, l4 * 8);
      bf8v bwv[2];
#pragma unroll
      for (int nj = 0; nj < 2; ++nj) {
        int t = wv * 2 + nj;
        bwv[nj] = *(const bf8v*)(wp + (((t * 4 + kt) * 64 + ln) << 3));
      }
#pragma unroll
      for (int mt = 0; mt < 4; ++mt)
#pragma unroll
        for (int nj = 0; nj < 2; ++nj)
          pacc[mt][nj] = mfma16(a[mt], bwv[nj], pacc[mt][nj]);
    }
    float* ob = out + (size_t)b * (49 * 128);
#pragma unroll
    for (int nj = 0; nj < 2; ++nj) {
      int c = (wv * 2 + nj) * 16 + l16;
      float pb = proj_b[c];
#pragma unroll
      for (int mt = 0; mt < 4; ++mt) {
#pragma unroll
        for (int r = 0; r < 4; ++r) {
          int row = mt * 16 + l4 * 4 + r;
          if (row < 49) ob[row * 128 + c] = pacc[mt][nj][r] + pb;
        }
      }
    }
  }
}

extern "C" void kernel_launch(void* const* d_in, const int* in_sizes, int n_in,
                              void* d_out, int out_size, void* d_ws, size_t ws_size,
                              hipStream_t stream) {
  const float* x          = (const float*)d_in[0];
  const float* mask       = (const float*)d_in[1];
  const float* qkv_w      = (const float*)d_in[2];
  const float* qkv_b      = (const float*)d_in[3];
  const float* proj_w     = (const float*)d_in[4];
  const float* proj_b     = (const float*)d_in[5];
  const float* bias_table = (const float*)d_in[6];

  char* ws = (char*)d_ws;
  bf16_t* wq = (bf16_t*)ws;                       // 24*4*64*8 bf16 = 98304 B
  bf16_t* wp = (bf16_t*)(ws + 98304);             // 8*4*64*8 bf16  = 32768 B
  float*  cbs = (float*)(ws + 131072);            // 64*4*64*64 f32 = 4 MiB

  prep_kernel<<<1024, 256, 0, stream>>>(mask, qkv_w, proj_w, bias_table, wq, wp, cbs);
  msa_kernel<<<4096, 256, 0, stream>>>(x, qkv_b, proj_b, wq, wp, cbs, (float*)d_out);
}

// Round 2
// 282.747 us; speedup vs baseline: 1.1211x; 1.1211x over previous
//
#include <hip/hip_runtime.h>

// WindowMSA fused kernel for MI355X (gfx950).
// One block = one window (B=4096). 4 waves = 4 heads, each wave owns its head.
// R5: x staged to LDS once (coalesced); V^T aliases the x-stage region
//     (barrier after last As read); multiplicative exp'd bias (no clamps);
//     deferred softmax normalization via ones-MFMA row sums (no shuffles).
//     LDS 37,888 B => 4 blocks/CU; 3 barriers total.

typedef __bf16 bf16_t;
typedef __bf16 bf8v  __attribute__((ext_vector_type(8)));
typedef __bf16 bf4v  __attribute__((ext_vector_type(4)));
typedef float  f4v   __attribute__((ext_vector_type(4)));

#define QK_SCALE 0.17677669529663687f  // 1/sqrt(32)

__device__ __forceinline__ f4v mfma16(bf8v a, bf8v b, f4v c) {
  return __builtin_amdgcn_mfma_f32_16x16x32_bf16(a, b, c, 0, 0, 0);
}

__device__ __forceinline__ bf8v join8(bf4v lo, bf4v hi) {
  return __builtin_shufflevector(lo, hi, 0, 1, 2, 3, 4, 5, 6, 7);
}

// ---------------- prep: swizzle weights to B-fragment order, build exp'd CB ----------------
// wq: [t<24][kt<4][lane<64][j<8]  = bf16(qkv_w[t*16+(l&15)][kt*32+(l>>4)*8+j])
// wp: [t<8 ][kt<4][lane<64][j<8]  = bf16(proj_w[...same...])
// cbs: [w<64][h<4][n<64][l16<16][nt<4] fp32 = exp(bias+mask) at m = nt*16+l16
//      (0 for m>=49; 1 for n>=49,m<49) -- MFMA lane order => float4 loads.
__global__ void prep_kernel(const float* __restrict__ mask,
                            const float* __restrict__ qkv_w,
                            const float* __restrict__ proj_w,
                            const float* __restrict__ bias_table,
                            bf16_t* __restrict__ wq,
                            bf16_t* __restrict__ wp,
                            float* __restrict__ cbs) {
  const int stride = gridDim.x * blockDim.x;
  const int tid0 = blockIdx.x * blockDim.x + threadIdx.x;
  for (int i = tid0; i < 24 * 4 * 64 * 8; i += stride) {
    int j = i & 7, l = (i >> 3) & 63, kt = (i >> 9) & 3, t = i >> 11;
    int n = t * 16 + (l & 15), k = kt * 32 + (l >> 4) * 8 + j;
    wq[i] = (bf16_t)qkv_w[n * 128 + k];
  }
  for (int i = tid0; i < 8 * 4 * 64 * 8; i += stride) {
    int j = i & 7, l = (i >> 3) & 63, kt = (i >> 9) & 3, t = i >> 11;
    int n = t * 16 + (l & 15), k = kt * 32 + (l >> 4) * 8 + j;
    wp[i] = (bf16_t)proj_w[n * 128 + k];
  }
  for (int i = tid0; i < 64 * 4 * 64 * 64; i += stride) {
    int j = i & 63;                 // l16*4 + nt
    int l16 = j >> 2, nt = j & 3;
    int m = nt * 16 + l16;
    int n = (i >> 6) & 63, h = (i >> 12) & 3, w = i >> 14;
    float v;
    if (m >= 49) {
      v = 0.0f;                      // padded key columns contribute nothing
    } else if (n >= 49) {
      v = 1.0f;                      // padded query rows: benign
    } else {
      int cn = 13 * (n / 7) + n % 7;
      int mm = 48 - m;
      int cm = 13 * (mm / 7) + mm % 7;
      // exp(bias+mask): masked (-100) -> ~3.7e-44 (matches old -80 clamp scale)
      v = __expf(bias_table[(cn + cm) * 4 + h] + mask[(w * 49 + n) * 49 + m]);
    }
    cbs[i] = v;
  }
}

// ---------------- fused window MSA ----------------
__global__ __launch_bounds__(256, 4) void msa_kernel(
    const float* __restrict__ x,
    const float* __restrict__ qkv_b,
    const float* __restrict__ proj_b,
    const bf16_t* __restrict__ wq,
    const bf16_t* __restrict__ wp,
    const float* __restrict__ cbs,
    float* __restrict__ out) {
  // gA (17,408 B): x-stage As[64][136]; aliased by V^T[4][32][68] after
  //   barrier-2 (all As reads complete at end of pass 2).
  // gT (4 x 5,120 B wave-private slabs): T[64][40] scratch hosting, in order,
  //   K -> Q -> P(half0) -> P(half1) -> O. Wave-private until barrier-3;
  //   proj reads all 4 slabs after it.
  __shared__ __align__(16) bf16_t gA[8704];
  __shared__ __align__(16) bf16_t gT[4][2560];

#define AS(r, c)    gA[(r) * 136 + (c)]
#define VTT(hh, d, t) gA[((hh) * 32 + (d)) * 68 + (t)]
#define TT(hh, r, c)  gT[hh][(r) * 40 + (c)]

  const int tid = threadIdx.x;
  const int wv  = tid >> 6;   // wave 0..3 == head
  const int ln  = tid & 63;
  const int l16 = ln & 15;
  const int l4  = ln >> 4;    // 0..3
  const int b   = blockIdx.x;
  const int w   = b & 63;     // mask window index
  const int h   = wv;

  // ---- Phase 1: x -> As (bf16), zero pad rows 49..63 ----
  {
    const float4* xb = (const float4*)(x + (size_t)b * (49 * 128));
    for (int i = tid; i < 64 * 32; i += 256) {
      int r = i >> 5, c4 = (i & 31) << 2;
      float4 v;
      if (r < 49) v = xb[(r * 128 + c4) >> 2];
      else        v = make_float4(0.f, 0.f, 0.f, 0.f);
      bf4v o = { (bf16_t)v.x, (bf16_t)v.y, (bf16_t)v.z, (bf16_t)v.w };
      *(bf4v*)&AS(r, c4) = o;
    }
  }
  __syncthreads();

  // ---- pass 1: Q_h, K_h  (M=64 tokens, N=64 ch, K=128) ----
  f4v acc[4][4];   // [ti: 0,1 = Q d-tiles; 2,3 = K d-tiles][mt]
#pragma unroll
  for (int ti = 0; ti < 4; ++ti)
#pragma unroll
    for (int mt = 0; mt < 4; ++mt) acc[ti][mt] = (f4v){0.f, 0.f, 0.f, 0.f};
#pragma unroll
  for (int kt = 0; kt < 4; ++kt) {
    bf8v a[4];
#pragma unroll
    for (int mt = 0; mt < 4; ++mt)
      a[mt] = *(const bf8v*)&AS(mt * 16 + l16, kt * 32 + l4 * 8);
    bf8v bb[4];
#pragma unroll
    for (int ti = 0; ti < 4; ++ti) {
      int t = (ti < 2) ? (2 * h + ti) : (8 + 2 * h + (ti - 2));
      bb[ti] = *(const bf8v*)(wq + (((t * 4 + kt) * 64 + ln) << 3));
    }
#pragma unroll
    for (int ti = 0; ti < 4; ++ti)
#pragma unroll
      for (int mt = 0; mt < 4; ++mt)
        acc[ti][mt] = mfma16(a[mt], bb[ti], acc[ti][mt]);
  }

  // ---- K -> T -> kf frags ----
  bf8v kf[4], qf[4];
#pragma unroll
  for (int ti = 0; ti < 2; ++ti) {
    float bias = qkv_b[128 + 32 * h + ti * 16 + l16];
#pragma unroll
    for (int mt = 0; mt < 4; ++mt)
#pragma unroll
      for (int r = 0; r < 4; ++r)
        TT(h, mt * 16 + l4 * 4 + r, ti * 16 + l16) = (bf16_t)(acc[2 + ti][mt][r] + bias);
  }
#pragma unroll
  for (int mt = 0; mt < 4; ++mt)
    kf[mt] = *(const bf8v*)&TT(h, mt * 16 + l16, l4 * 8);

  // ---- Q -> T -> qf frags (overwrites K copy; in-wave DS order) ----
#pragma unroll
  for (int ti = 0; ti < 2; ++ti) {
    float bias = qkv_b[32 * h + ti * 16 + l16];
#pragma unroll
    for (int mt = 0; mt < 4; ++mt)
#pragma unroll
      for (int r = 0; r < 4; ++r)
        TT(h, mt * 16 + l4 * 4 + r, ti * 16 + l16) =
            (bf16_t)((acc[ti][mt][r] + bias) * QK_SCALE);
  }
#pragma unroll
  for (int mt = 0; mt < 4; ++mt)
    qf[mt] = *(const bf8v*)&TT(h, mt * 16 + l16, l4 * 8);

  // ---- QK^T: row = mt*16+l4*4+r, col = nt*16+l16 ----
  f4v lg[4][4];
#pragma unroll
  for (int mt = 0; mt < 4; ++mt)
#pragma unroll
    for (int nt = 0; nt < 4; ++nt)
      lg[mt][nt] = mfma16(qf[mt], kf[nt], (f4v){0.f, 0.f, 0.f, 0.f});

  // ---- softmax numerator: P = exp(S) * Ecb, UNNORMALIZED (deferred norm).
  //      half0 (m<32) -> T; half1 kept in regs. No shuffles, no clamps.
  const float* cbp = cbs + ((size_t)(w * 4 + h) << 12);
  float ph1[4][4][2];
#pragma unroll
  for (int mt = 0; mt < 4; ++mt) {
#pragma unroll
    for (int r = 0; r < 4; ++r) {
      int row = mt * 16 + l4 * 4 + r;
      float4 e = *(const float4*)(cbp + (row << 6) + l16 * 4);
      float p0 = __expf(lg[mt][0][r]) * e.x;
      float p1 = __expf(lg[mt][1][r]) * e.y;
      float p2 = __expf(lg[mt][2][r]) * e.z;
      float p3 = __expf(lg[mt][3][r]) * e.w;
      TT(h, row, l16)      = (bf16_t)p0;
      TT(h, row, 16 + l16) = (bf16_t)p1;
      ph1[mt][r][0] = p2;
      ph1[mt][r][1] = p3;
    }
  }

  // ---- pass 2: V_h (re-reads As via LDS; last As use) ----
  f4v vacc[2][4];
#pragma unroll
  for (int ti = 0; ti < 2; ++ti)
#pragma unroll
    for (int mt = 0; mt < 4; ++mt) vacc[ti][mt] = (f4v){0.f, 0.f, 0.f, 0.f};
#pragma unroll
  for (int kt = 0; kt < 4; ++kt) {
    bf8v a[4];
#pragma unroll
    for (int mt = 0; mt < 4; ++mt)
      a[mt] = *(const bf8v*)&AS(mt * 16 + l16, kt * 32 + l4 * 8);
    bf8v bb[2];
#pragma unroll
    for (int ti = 0; ti < 2; ++ti) {
      int t = 16 + 2 * h + ti;
      bb[ti] = *(const bf8v*)(wq + (((t * 4 + kt) * 64 + ln) << 3));
    }
#pragma unroll
    for (int ti = 0; ti < 2; ++ti)
#pragma unroll
      for (int mt = 0; mt < 4; ++mt)
        vacc[ti][mt] = mfma16(a[mt], bb[ti], vacc[ti][mt]);
  }

  __syncthreads();   // barrier-2: all As reads done -> V^T may alias gA

  // ---- V^T epilogue: VTT[d][token], b64 vector stores ----
#pragma unroll
  for (int ti = 0; ti < 2; ++ti) {
    float bias = qkv_b[256 + 32 * h + ti * 16 + l16];
#pragma unroll
    for (int mt = 0; mt < 4; ++mt) {
      bf4v o = { (bf16_t)(vacc[ti][mt][0] + bias), (bf16_t)(vacc[ti][mt][1] + bias),
                 (bf16_t)(vacc[ti][mt][2] + bias), (bf16_t)(vacc[ti][mt][3] + bias) };
      *(bf4v*)&VTT(h, ti * 16 + l16, mt * 16 + l4 * 4) = o;
    }
  }

  // ---- PV + row-sum MFMAs: O = P @ V, s = P @ 1; two k-halves through T ----
  const bf16_t one16 = (bf16_t)1.0f;
  const bf8v ones = { one16, one16, one16, one16, one16, one16, one16, one16 };
  f4v oc[4][2], sacc[4];
#pragma unroll
  for (int nt = 0; nt < 4; ++nt) {
    sacc[nt] = (f4v){0.f, 0.f, 0.f, 0.f};
#pragma unroll
    for (int dt = 0; dt < 2; ++dt) oc[nt][dt] = (f4v){0.f, 0.f, 0.f, 0.f};
  }
  {
    bf8v pf[4], vf[2];
#pragma unroll
    for (int nt = 0; nt < 4; ++nt) pf[nt] = *(const bf8v*)&TT(h, nt * 16 + l16, l4 * 8);
#pragma unroll
    for (int dt = 0; dt < 2; ++dt)
      vf[dt] = join8(*(const bf4v*)&VTT(h, dt * 16 + l16, l4 * 8),
                     *(const bf4v*)&VTT(h, dt * 16 + l16, l4 * 8 + 4));
#pragma unroll
    for (int nt = 0; nt < 4; ++nt) {
#pragma unroll
      for (int dt = 0; dt < 2; ++dt) oc[nt][dt] = mfma16(pf[nt], vf[dt], oc[nt][dt]);
      sacc[nt] = mfma16(pf[nt], ones, sacc[nt]);
    }
    // stage half1 (m in 32..63) over T
#pragma unroll
    for (int mt = 0; mt < 4; ++mt)
#pragma unroll
      for (int r = 0; r < 4; ++r) {
        int row = mt * 16 + l4 * 4 + r;
        TT(h, row, l16)      = (bf16_t)ph1[mt][r][0];
        TT(h, row, 16 + l16) = (bf16_t)ph1[mt][r][1];
      }
#pragma unroll
    for (int nt = 0; nt < 4; ++nt) pf[nt] = *(const bf8v*)&TT(h, nt * 16 + l16, l4 * 8);
#pragma unroll
    for (int dt = 0; dt < 2; ++dt)
      vf[dt] = join8(*(const bf4v*)&VTT(h, dt * 16 + l16, 32 + l4 * 8),
                     *(const bf4v*)&VTT(h, dt * 16 + l16, 32 + l4 * 8 + 4));
#pragma unroll
    for (int nt = 0; nt < 4; ++nt) {
#pragma unroll
      for (int dt = 0; dt < 2; ++dt) oc[nt][dt] = mfma16(pf[nt], vf[dt], oc[nt][dt]);
      sacc[nt] = mfma16(pf[nt], ones, sacc[nt]);
    }
  }

  // ---- normalize + O -> T (cols 0..31 of head's slab) ----
#pragma unroll
  for (int nt = 0; nt < 4; ++nt) {
    float inv[4];
#pragma unroll
    for (int r = 0; r < 4; ++r) inv[r] = 1.0f / sacc[nt][r];
#pragma unroll
    for (int dt = 0; dt < 2; ++dt)
#pragma unroll
      for (int r = 0; r < 4; ++r)
        TT(h, nt * 16 + l4 * 4 + r, dt * 16 + l16) = (bf16_t)(oc[nt][dt][r] * inv[r]);
  }

  __syncthreads();   // barrier-3: O slabs -> proj

  // ---- proj GEMM (M=64, N=128, K=128); wave handles 2 n-tiles ----
  {
    f4v pacc[4][2];
#pragma unroll
    for (int mt = 0; mt < 4; ++mt)
#pragma unroll
      for (int nj = 0; nj < 2; ++nj) pacc[mt][nj] = (f4v){0.f, 0.f, 0.f, 0.f};
#pragma unroll
    for (int kt = 0; kt < 4; ++kt) {
      bf8v a[4];
#pragma unroll
      for (int mt = 0; mt < 4; ++mt)
        a[mt] = *(const bf8v*)&TT(kt, mt * 16 + l16, l4 * 8);
      bf8v bwv[2];
#pragma unroll
      for (int nj = 0; nj < 2; ++nj) {
        int t = wv * 2 + nj;
        bwv[nj] = *(const bf8v*)(wp + (((t * 4 + kt) * 64 + ln) << 3));
      }
#pragma unroll
      for (int mt = 0; mt < 4; ++mt)
#pragma unroll
        for (int nj = 0; nj < 2; ++nj)
          pacc[mt][nj] = mfma16(a[mt], bwv[nj], pacc[mt][nj]);
    }
    float* ob = out + (size_t)b * (49 * 128);
#pragma unroll
    for (int nj = 0; nj < 2; ++nj) {
      int c = (wv * 2 + nj) * 16 + l16;
      float pb = proj_b[c];
#pragma unroll
      for (int mt = 0; mt < 4; ++mt) {
#pragma unroll
        for (int r = 0; r < 4; ++r) {
          int row = mt * 16 + l4 * 4 + r;
          if (row < 49) ob[row * 128 + c] = pacc[mt][nj][r] + pb;
        }
      }
    }
  }
}

extern "C" void kernel_launch(void* const* d_in, const int* in_sizes, int n_in,
                              void* d_out, int out_size, void* d_ws, size_t ws_size,
                              hipStream_t stream) {
  const float* x          = (const float*)d_in[0];
  const float* mask       = (const float*)d_in[1];
  const float* qkv_w      = (const float*)d_in[2];
  const float* qkv_b      = (const float*)d_in[3];
  const float* proj_w     = (const float*)d_in[4];
  const float* proj_b     = (const float*)d_in[5];
  const float* bias_table = (const float*)d_in[6];

  char* ws = (char*)d_ws;
  bf16_t* wq = (bf16_t*)ws;                       // 24*4*64*8 bf16 = 98304 B
  bf16_t* wp = (bf16_t*)(ws + 98304);             // 8*4*64*8 bf16  = 32768 B
  float*  cbs = (float*)(ws + 131072);            // 64*4*64*64 f32 = 4 MiB

  prep_kernel<<<1024, 256, 0, stream>>>(mask, qkv_w, proj_w, bias_table, wq, wp, cbs);
  msa_kernel<<<4096, 256, 0, stream>>>(x, qkv_b, proj_b, wq, wp, cbs, (float*)d_out);
}

// Round 3
// 264.630 us; speedup vs baseline: 1.1979x; 1.0685x over previous
//
#include <hip/hip_runtime.h>

// WindowMSA fused kernel for MI355X (gfx950).
// One block = one window (B=4096). 4 waves = 4 heads, each wave owns its head.
// R6: operand-swapped MFMAs (compute Q^T/K^T, S^T, O^T) so every LDS epilogue
//     is a transposed b64 vector store (40 ds ops/wave vs 160 scalar b16);
//     cbs re-laid out for swapped lane order; 1 rcp per 16 queries.
//     LDS 38,912 B => 4 blocks/CU; 3 barriers total.

typedef __bf16 bf16_t;
typedef __bf16 bf8v  __attribute__((ext_vector_type(8)));
typedef __bf16 bf4v  __attribute__((ext_vector_type(4)));
typedef float  f4v   __attribute__((ext_vector_type(4)));

#define QK_SCALE 0.17677669529663687f  // 1/sqrt(32)

__device__ __forceinline__ f4v mfma16(bf8v a, bf8v b, f4v c) {
  return __builtin_amdgcn_mfma_f32_16x16x32_bf16(a, b, c, 0, 0, 0);
}

// ---------------- prep: swizzle weights to fragment order, build exp'd CB ----------------
// wq: [t<24][kt<4][lane<64][j<8]  = bf16(qkv_w[t*16+(l&15)][kt*32+(l>>4)*8+j])
// wp: [t<8 ][kt<4][lane<64][j<8]  = bf16(proj_w[...same...])
// cbs: [w<64][h<4][nt<4][mt<4][ln<64][r<4] fp32 = exp(bias+mask) at
//      query n = 16nt+(ln&15), key m = 16mt+4*(ln>>4)+r  (swapped-QK^T lane order)
//      (0 for m>=49; 1 for n>=49,m<49) => float4 loads in msa.
__global__ void prep_kernel(const float* __restrict__ mask,
                            const float* __restrict__ qkv_w,
                            const float* __restrict__ proj_w,
                            const float* __restrict__ bias_table,
                            bf16_t* __restrict__ wq,
                            bf16_t* __restrict__ wp,
                            float* __restrict__ cbs) {
  const int stride = gridDim.x * blockDim.x;
  const int tid0 = blockIdx.x * blockDim.x + threadIdx.x;
  for (int i = tid0; i < 24 * 4 * 64 * 8; i += stride) {
    int j = i & 7, l = (i >> 3) & 63, kt = (i >> 9) & 3, t = i >> 11;
    int n = t * 16 + (l & 15), k = kt * 32 + (l >> 4) * 8 + j;
    wq[i] = (bf16_t)qkv_w[n * 128 + k];
  }
  for (int i = tid0; i < 8 * 4 * 64 * 8; i += stride) {
    int j = i & 7, l = (i >> 3) & 63, kt = (i >> 9) & 3, t = i >> 11;
    int n = t * 16 + (l & 15), k = kt * 32 + (l >> 4) * 8 + j;
    wp[i] = (bf16_t)proj_w[n * 128 + k];
  }
  for (int i = tid0; i < 64 * 4 * 4 * 4 * 64 * 4; i += stride) {
    int r  = i & 3;
    int ln = (i >> 2) & 63;
    int mt = (i >> 8) & 3;
    int nt = (i >> 10) & 3;
    int h  = (i >> 12) & 3;
    int w  = i >> 14;
    int n = nt * 16 + (ln & 15);          // query
    int m = mt * 16 + (ln >> 4) * 4 + r;  // key
    float v;
    if (m >= 49) {
      v = 0.0f;                      // padded key columns contribute nothing
    } else if (n >= 49) {
      v = 1.0f;                      // padded query rows: benign
    } else {
      int cn = 13 * (n / 7) + n % 7;
      int mm = 48 - m;
      int cm = 13 * (mm / 7) + mm % 7;
      v = __expf(bias_table[(cn + cm) * 4 + h] + mask[(w * 49 + n) * 49 + m]);
    }
    cbs[i] = v;
  }
}

// ---------------- fused window MSA ----------------
__global__ __launch_bounds__(256, 4) void msa_kernel(
    const float* __restrict__ x,
    const float* __restrict__ qkv_b,
    const float* __restrict__ proj_b,
    const bf16_t* __restrict__ wq,
    const bf16_t* __restrict__ wp,
    const float* __restrict__ cbs,
    float* __restrict__ out) {
  // gA (18,432 B): x-stage As[64][136] (17,408 B used); aliased by
  //   V^T[4][32][72] after barrier-2 (all As reads complete by then).
  // gT (4 x 5,120 B wave-private slabs): T[64][40] hosting, in order,
  //   K[tok][d] -> Q[tok][d] -> P(half0) -> P(half1) -> O[tok][d].
  //   Wave-private until barrier-3; proj reads all 4 slabs after it.
  __shared__ __align__(16) bf16_t gA[9216];
  __shared__ __align__(16) bf16_t gT[4][2560];

#define AS(r, c)      gA[(r) * 136 + (c)]
#define VTT(hh, d, t) gA[((hh) * 32 + (d)) * 72 + (t)]
#define TT(hh, r, c)  gT[hh][(r) * 40 + (c)]

  const int tid = threadIdx.x;
  const int wv  = tid >> 6;   // wave 0..3 == head
  const int ln  = tid & 63;
  const int l16 = ln & 15;
  const int l4  = ln >> 4;    // 0..3
  const int b   = blockIdx.x;
  const int w   = b & 63;     // mask window index
  const int h   = wv;

  // ---- Phase 1: x -> As (bf16), zero pad rows 49..63 ----
  {
    const float4* xb = (const float4*)(x + (size_t)b * (49 * 128));
    for (int i = tid; i < 64 * 32; i += 256) {
      int r = i >> 5, c4 = (i & 31) << 2;
      float4 v;
      if (r < 49) v = xb[(r * 128 + c4) >> 2];
      else        v = make_float4(0.f, 0.f, 0.f, 0.f);
      bf4v o = { (bf16_t)v.x, (bf16_t)v.y, (bf16_t)v.z, (bf16_t)v.w };
      *(bf4v*)&AS(r, c4) = o;
    }
  }
  __syncthreads();

  // ---- pass 1 (SWAPPED): Q^T_h, K^T_h = W @ X^T  (rows=chan, cols=token) ----
  f4v acc[4][4];   // [ti: 0,1 = Q d-tiles; 2,3 = K d-tiles][mt(token tile)]
#pragma unroll
  for (int ti = 0; ti < 4; ++ti)
#pragma unroll
    for (int mt = 0; mt < 4; ++mt) acc[ti][mt] = (f4v){0.f, 0.f, 0.f, 0.f};
#pragma unroll
  for (int kt = 0; kt < 4; ++kt) {
    bf8v a[4];
#pragma unroll
    for (int mt = 0; mt < 4; ++mt)
      a[mt] = *(const bf8v*)&AS(mt * 16 + l16, kt * 32 + l4 * 8);
    bf8v bb[4];
#pragma unroll
    for (int ti = 0; ti < 4; ++ti) {
      int t = (ti < 2) ? (2 * h + ti) : (8 + 2 * h + (ti - 2));
      bb[ti] = *(const bf8v*)(wq + (((t * 4 + kt) * 64 + ln) << 3));
    }
#pragma unroll
    for (int ti = 0; ti < 4; ++ti)
#pragma unroll
      for (int mt = 0; mt < 4; ++mt)
        acc[ti][mt] = mfma16(bb[ti], a[mt], acc[ti][mt]);   // W as A => rows=chan
  }

  // ---- K epilogue: transposed b64 stores -> K[tok][d], then kf frags ----
  bf8v kf[4], qf[4];
#pragma unroll
  for (int ti = 0; ti < 2; ++ti) {
    float4 kb = *(const float4*)(qkv_b + 128 + 32 * h + 16 * ti + 4 * l4);
#pragma unroll
    for (int mt = 0; mt < 4; ++mt) {
      f4v v = acc[2 + ti][mt];
      bf4v o = { (bf16_t)(v[0] + kb.x), (bf16_t)(v[1] + kb.y),
                 (bf16_t)(v[2] + kb.z), (bf16_t)(v[3] + kb.w) };
      *(bf4v*)&TT(h, mt * 16 + l16, ti * 16 + 4 * l4) = o;
    }
  }
#pragma unroll
  for (int mt = 0; mt < 4; ++mt)
    kf[mt] = *(const bf8v*)&TT(h, mt * 16 + l16, l4 * 8);

  // ---- Q epilogue (overwrites K copy; in-wave DS order) ----
#pragma unroll
  for (int ti = 0; ti < 2; ++ti) {
    float4 qb = *(const float4*)(qkv_b + 32 * h + 16 * ti + 4 * l4);
#pragma unroll
    for (int mt = 0; mt < 4; ++mt) {
      f4v v = acc[ti][mt];
      bf4v o = { (bf16_t)((v[0] + qb.x) * QK_SCALE), (bf16_t)((v[1] + qb.y) * QK_SCALE),
                 (bf16_t)((v[2] + qb.z) * QK_SCALE), (bf16_t)((v[3] + qb.w) * QK_SCALE) };
      *(bf4v*)&TT(h, mt * 16 + l16, ti * 16 + 4 * l4) = o;
    }
  }
#pragma unroll
  for (int mt = 0; mt < 4; ++mt)
    qf[mt] = *(const bf8v*)&TT(h, mt * 16 + l16, l4 * 8);

  // ---- QK^T (SWAPPED): lg[mtk][nt] lane reg r = P-logit[query=16nt+l16][key=16mtk+4l4+r]
  f4v lg[4][4];
#pragma unroll
  for (int mtk = 0; mtk < 4; ++mtk)
#pragma unroll
    for (int nt = 0; nt < 4; ++nt)
      lg[mtk][nt] = mfma16(kf[mtk], qf[nt], (f4v){0.f, 0.f, 0.f, 0.f});

  // ---- softmax numerator: P = exp(S)*Ecb, UNNORMALIZED; in-place in lg ----
  const float* cbp = cbs + ((size_t)(w * 4 + h) << 12);
#pragma unroll
  for (int nt = 0; nt < 4; ++nt) {
#pragma unroll
    for (int mtk = 0; mtk < 4; ++mtk) {
      float4 e = *(const float4*)(cbp + ((((nt * 4 + mtk) << 6) | ln) << 2));
      lg[mtk][nt][0] = __expf(lg[mtk][nt][0]) * e.x;
      lg[mtk][nt][1] = __expf(lg[mtk][nt][1]) * e.y;
      lg[mtk][nt][2] = __expf(lg[mtk][nt][2]) * e.z;
      lg[mtk][nt][3] = __expf(lg[mtk][nt][3]) * e.w;
    }
  }
  // write P half0 (keys 0..31 = mtk 0,1) -> T cols 0..31, b64 stores
#pragma unroll
  for (int nt = 0; nt < 4; ++nt)
#pragma unroll
    for (int mtk = 0; mtk < 2; ++mtk) {
      f4v p = lg[mtk][nt];
      bf4v o = { (bf16_t)p[0], (bf16_t)p[1], (bf16_t)p[2], (bf16_t)p[3] };
      *(bf4v*)&TT(h, nt * 16 + l16, mtk * 16 + 4 * l4) = o;
    }

  // ---- pass 2: V_h (unswapped; re-reads As via LDS; last As use) ----
  f4v vacc[2][4];
#pragma unroll
  for (int ti = 0; ti < 2; ++ti)
#pragma unroll
    for (int mt = 0; mt < 4; ++mt) vacc[ti][mt] = (f4v){0.f, 0.f, 0.f, 0.f};
#pragma unroll
  for (int kt = 0; kt < 4; ++kt) {
    bf8v a[4];
#pragma unroll
    for (int mt = 0; mt < 4; ++mt)
      a[mt] = *(const bf8v*)&AS(mt * 16 + l16, kt * 32 + l4 * 8);
    bf8v bb[2];
#pragma unroll
    for (int ti = 0; ti < 2; ++ti) {
      int t = 16 + 2 * h + ti;
      bb[ti] = *(const bf8v*)(wq + (((t * 4 + kt) * 64 + ln) << 3));
    }
#pragma unroll
    for (int ti = 0; ti < 2; ++ti)
#pragma unroll
      for (int mt = 0; mt < 4; ++mt)
        vacc[ti][mt] = mfma16(a[mt], bb[ti], vacc[ti][mt]);
  }

  __syncthreads();   // barrier-2: all As reads done -> V^T may alias gA

  // ---- V^T epilogue: VTT[d][token], b64 stores ----
#pragma unroll
  for (int ti = 0; ti < 2; ++ti) {
    float bias = qkv_b[256 + 32 * h + ti * 16 + l16];
#pragma unroll
    for (int mt = 0; mt < 4; ++mt) {
      bf4v o = { (bf16_t)(vacc[ti][mt][0] + bias), (bf16_t)(vacc[ti][mt][1] + bias),
                 (bf16_t)(vacc[ti][mt][2] + bias), (bf16_t)(vacc[ti][mt][3] + bias) };
      *(bf4v*)&VTT(h, ti * 16 + l16, mt * 16 + l4 * 4) = o;
    }
  }

  // ---- PV (SWAPPED): O^T = V^T @ P^T ; s = 1 @ P^T ; two k-halves ----
  const bf16_t one16 = (bf16_t)1.0f;
  const bf8v ones = { one16, one16, one16, one16, one16, one16, one16, one16 };
  f4v oc[2][4], sacc[4];   // oc[dt][nt] lane reg r = O^T[16dt+4l4+r][16nt+l16]
#pragma unroll
  for (int nt = 0; nt < 4; ++nt) {
    sacc[nt] = (f4v){0.f, 0.f, 0.f, 0.f};
#pragma unroll
    for (int dt = 0; dt < 2; ++dt) oc[dt][nt] = (f4v){0.f, 0.f, 0.f, 0.f};
  }
  {
    bf8v pf[4], vf[2];
#pragma unroll
    for (int nt = 0; nt < 4; ++nt) pf[nt] = *(const bf8v*)&TT(h, nt * 16 + l16, l4 * 8);
#pragma unroll
    for (int dt = 0; dt < 2; ++dt) vf[dt] = *(const bf8v*)&VTT(h, dt * 16 + l16, l4 * 8);
#pragma unroll
    for (int dt = 0; dt < 2; ++dt)
#pragma unroll
      for (int nt = 0; nt < 4; ++nt) oc[dt][nt] = mfma16(vf[dt], pf[nt], oc[dt][nt]);
#pragma unroll
    for (int nt = 0; nt < 4; ++nt) sacc[nt] = mfma16(ones, pf[nt], sacc[nt]);
    // stage P half1 (keys 32..63 = mtk 2,3) over T cols 0..31
#pragma unroll
    for (int nt = 0; nt < 4; ++nt)
#pragma unroll
      for (int mtk = 2; mtk < 4; ++mtk) {
        f4v p = lg[mtk][nt];
        bf4v o = { (bf16_t)p[0], (bf16_t)p[1], (bf16_t)p[2], (bf16_t)p[3] };
        *(bf4v*)&TT(h, nt * 16 + l16, (mtk - 2) * 16 + 4 * l4) = o;
      }
#pragma unroll
    for (int nt = 0; nt < 4; ++nt) pf[nt] = *(const bf8v*)&TT(h, nt * 16 + l16, l4 * 8);
#pragma unroll
    for (int dt = 0; dt < 2; ++dt) vf[dt] = *(const bf8v*)&VTT(h, dt * 16 + l16, 32 + l4 * 8);
#pragma unroll
    for (int dt = 0; dt < 2; ++dt)
#pragma unroll
      for (int nt = 0; nt < 4; ++nt) oc[dt][nt] = mfma16(vf[dt], pf[nt], oc[dt][nt]);
#pragma unroll
    for (int nt = 0; nt < 4; ++nt) sacc[nt] = mfma16(ones, pf[nt], sacc[nt]);
  }

  // ---- normalize (1 rcp per nt) + transposed b64 store: O[tok][d] ----
#pragma unroll
  for (int nt = 0; nt < 4; ++nt) {
    float inv = 1.0f / sacc[nt][0];
#pragma unroll
    for (int dt = 0; dt < 2; ++dt) {
      f4v v = oc[dt][nt];
      bf4v o = { (bf16_t)(v[0] * inv), (bf16_t)(v[1] * inv),
                 (bf16_t)(v[2] * inv), (bf16_t)(v[3] * inv) };
      *(bf4v*)&TT(h, nt * 16 + l16, dt * 16 + 4 * l4) = o;
    }
  }

  __syncthreads();   // barrier-3: O slabs -> proj

  // ---- proj GEMM (M=64, N=128, K=128); wave handles 2 n-tiles ----
  {
    f4v pacc[4][2];
#pragma unroll
    for (int mt = 0; mt < 4; ++mt)
#pragma unroll
      for (int nj = 0; nj < 2; ++nj) pacc[mt][nj] = (f4v){0.f, 0.f, 0.f, 0.f};
#pragma unroll
    for (int kt = 0; kt < 4; ++kt) {
      bf8v a[4];
#pragma unroll
      for (int mt = 0; mt < 4; ++mt)
        a[mt] = *(const bf8v*)&TT(kt, mt * 16 + l16, l4 * 8);
      bf8v bwv[2];
#pragma unroll
      for (int nj = 0; nj < 2; ++nj) {
        int t = wv * 2 + nj;
        bwv[nj] = *(const bf8v*)(wp + (((t * 4 + kt) * 64 + ln) << 3));
      }
#pragma unroll
      for (int mt = 0; mt < 4; ++mt)
#pragma unroll
        for (int nj = 0; nj < 2; ++nj)
          pacc[mt][nj] = mfma16(a[mt], bwv[nj], pacc[mt][nj]);
    }
    float* ob = out + (size_t)b * (49 * 128);
#pragma unroll
    for (int nj = 0; nj < 2; ++nj) {
      int c = (wv * 2 + nj) * 16 + l16;
      float pb = proj_b[c];
#pragma unroll
      for (int mt = 0; mt < 4; ++mt) {
#pragma unroll
        for (int r = 0; r < 4; ++r) {
          int row = mt * 16 + l4 * 4 + r;
          if (row < 49) ob[row * 128 + c] = pacc[mt][nj][r] + pb;
        }
      }
    }
  }
}

extern "C" void kernel_launch(void* const* d_in, const int* in_sizes, int n_in,
                              void* d_out, int out_size, void* d_ws, size_t ws_size,
                              hipStream_t stream) {
  const float* x          = (const float*)d_in[0];
  const float* mask       = (const float*)d_in[1];
  const float* qkv_w      = (const float*)d_in[2];
  const float* qkv_b      = (const float*)d_in[3];
  const float* proj_w     = (const float*)d_in[4];
  const float* proj_b     = (const float*)d_in[5];
  const float* bias_table = (const float*)d_in[6];

  char* ws = (char*)d_ws;
  bf16_t* wq = (bf16_t*)ws;                       // 24*4*64*8 bf16 = 98304 B
  bf16_t* wp = (bf16_t*)(ws + 98304);             // 8*4*64*8 bf16  = 32768 B
  float*  cbs = (float*)(ws + 131072);            // 64*4*4*4*64*4 f32 = 4 MiB

  prep_kernel<<<1024, 256, 0, stream>>>(mask, qkv_w, proj_w, bias_table, wq, wp, cbs);
  msa_kernel<<<4096, 256, 0, stream>>>(x, qkv_b, proj_b, wq, wp, cbs, (float*)d_out);
}